// Round 1
// baseline (52.005 us; speedup 1.0000x reference)
//
#include <hip/hip_runtime.h>

#define KITER 20

// One thread per sample. fp32 throughout (no fp32 MFMA on CDNA4; bf16 split
// would risk the 2%-of-absmax threshold through 20 multiplicative VI steps).
__global__ __launch_bounds__(256, 3) void vpn_kernel(
    const float* __restrict__ obs,
    const float* __restrict__ W_phi,
    const float* __restrict__ b_phi,
    const float* __restrict__ W_logit,
    const float* __restrict__ b_logit,
    float* __restrict__ out, int B)
{
    // per-thread V spill area for the generic (idx!=0) extraction path.
    // stride 17 -> bank = (17*t + m) & 31, 17 odd => conflict-free (2-way max).
    __shared__ float vlds[256 * 17];

    const int t = threadIdx.x;
    const int smp = blockIdx.x * 256 + t;
    if (smp >= B) return;

    // ---- load obs row (48 floats) as 12 x float4 ----
    float o[48];
    const float4* o4 = reinterpret_cast<const float4*>(obs + (size_t)smp * 48);
    #pragma unroll
    for (int q = 0; q < 12; ++q) {
        float4 tt = o4[q];
        o[4*q+0] = tt.x; o[4*q+1] = tt.y; o[4*q+2] = tt.z; o[4*q+3] = tt.w;
    }

    // ---- agent position: first row-major cell with channel-1 != 0 ----
    int idx = 16;
    #pragma unroll
    for (int cell = 15; cell >= 0; --cell)
        if (o[cell*3 + 1] != 0.0f) idx = cell;
    const int ai = (idx == 16) ? 1 : (idx >> 2);
    const int aj = (idx == 16) ? 1 : (idx & 3);

    // ---- Phi: out[j] = b[j] + sum_k o[k] * W_phi[j*48+k]  (W via s_load) ----
    float ph[48];
    #pragma unroll
    for (int j = 0; j < 48; ++j) {
        float acc = b_phi[j];
        #pragma unroll
        for (int k = 0; k < 48; ++k)
            acc = fmaf(o[k], W_phi[j*48 + k], acc);
        ph[j] = acc;
    }

    // rin = ph[cell*3+0], rout = ph[cell*3+1], p = ph[cell*3+2]
    float p_[16];
    #pragma unroll
    for (int c = 0; c < 16; ++c) p_[c] = ph[c*3 + 2];

    // directions: (dh,dw) for the 4 shifts in the reference
    constexpr int DHs[4] = {0, 0, -1, 1};
    constexpr int DWs[4] = {-1, 1, 0, 0};

    // cdir[d][cell] = Rin(h+dh, w+dw) - rout[cell]   (Rin OOB = 0)
    float cdir[4][16];
    #pragma unroll
    for (int d = 0; d < 4; ++d) {
        #pragma unroll
        for (int h = 0; h < 4; ++h) {
            #pragma unroll
            for (int w = 0; w < 4; ++w) {
                const int hh = h + DHs[d], ww = w + DWs[d];
                float rn = 0.0f;
                if (hh >= 0 && hh < 4 && ww >= 0 && ww < 4)
                    rn = ph[(hh*4 + ww)*3 + 0];
                cdir[d][h*4 + w] = rn - ph[(h*4 + w)*3 + 1];
            }
        }
    }

    // ---- K=20 value-iteration steps, ping-pong v<->nv (no copies) ----
    float v[16], nv[16];
    #pragma unroll
    for (int c = 0; c < 16; ++c) v[c] = 0.0f;

#define VI_STEP(SRC, DST)                                                     \
    {                                                                         \
        _Pragma("unroll")                                                     \
        for (int h = 0; h < 4; ++h) {                                         \
            _Pragma("unroll")                                                 \
            for (int w = 0; w < 4; ++w) {                                     \
                const int cell = h*4 + w;                                     \
                float acc = SRC[cell];                                        \
                _Pragma("unroll")                                             \
                for (int d = 0; d < 4; ++d) {                                 \
                    const int hh = h + DHs[d], ww = w + DWs[d];               \
                    float t2;                                                 \
                    if (hh >= 0 && hh < 4 && ww >= 0 && ww < 4)               \
                        t2 = fmaf(p_[cell], SRC[hh*4 + ww], cdir[d][cell]);   \
                    else                                                      \
                        t2 = cdir[d][cell];                                   \
                    acc = fmaxf(acc, t2);                                     \
                }                                                             \
                DST[cell] = acc;                                              \
            }                                                                 \
        }                                                                     \
    }

    #pragma unroll 1
    for (int it = 0; it < KITER / 2; ++it) {
        VI_STEP(v, nv)
        VI_STEP(nv, v)
    }
#undef VI_STEP
    // final V lives in v[]; V[h][w] (post-transpose) = v[w*4 + h]

    // ---- extraction: logit_in[36] ----
    float li[36];
    if (idx == 0) {
        // fast path (ai=aj=0): window rows/cols -1..1; OOB -> 0; all static.
        #pragma unroll
        for (int a = 0; a < 3; ++a) {
            #pragma unroll
            for (int b = 0; b < 3; ++b) {
                const bool inb = (a >= 1) && (b >= 1);
                #pragma unroll
                for (int c = 0; c < 3; ++c)
                    li[a*9 + b*3 + c] = inb ? o[((a-1)*4 + (b-1))*3 + c] : 0.0f;
                li[27 + a*3 + b] = inb ? v[(b-1)*4 + (a-1)] : 0.0f;
            }
        }
    } else {
        // generic path: V through per-thread LDS (runtime index), obs re-read.
        #pragma unroll
        for (int h = 0; h < 4; ++h)
            #pragma unroll
            for (int w = 0; w < 4; ++w)
                vlds[t*17 + h*4 + w] = v[w*4 + h];   // store transposed V
        const float* orow = obs + (size_t)smp * 48;
        #pragma unroll
        for (int a = 0; a < 3; ++a) {
            #pragma unroll
            for (int b = 0; b < 3; ++b) {
                const int hh = ai + a - 1, ww = aj + b - 1;
                const bool inb = (hh >= 0) && (hh < 4) && (ww >= 0) && (ww < 4);
                const int cl = inb ? (hh*4 + ww) : 0;
                #pragma unroll
                for (int c = 0; c < 3; ++c)
                    li[a*9 + b*3 + c] = inb ? orow[cl*3 + c] : 0.0f;
                li[27 + a*3 + b] = inb ? vlds[t*17 + cl] : 0.0f;
            }
        }
    }

    // ---- logit: 4 x 36 matvec (W via s_load) + coalesced float4 store ----
    float lg[4];
    #pragma unroll
    for (int a = 0; a < 4; ++a) {
        float acc = b_logit[a];
        #pragma unroll
        for (int m = 0; m < 36; ++m)
            acc = fmaf(li[m], W_logit[a*36 + m], acc);
        lg[a] = acc;
    }
    *reinterpret_cast<float4*>(out + (size_t)smp * 4) =
        make_float4(lg[0], lg[1], lg[2], lg[3]);
}

extern "C" void kernel_launch(void* const* d_in, const int* in_sizes, int n_in,
                              void* d_out, int out_size, void* d_ws, size_t ws_size,
                              hipStream_t stream) {
    const float* obs     = (const float*)d_in[0];
    const float* W_phi   = (const float*)d_in[1];
    const float* b_phi   = (const float*)d_in[2];
    const float* W_logit = (const float*)d_in[3];
    const float* b_logit = (const float*)d_in[4];
    float* out = (float*)d_out;

    const int B = in_sizes[0] / 48;
    const int grid = (B + 255) / 256;
    vpn_kernel<<<grid, 256, 0, stream>>>(obs, W_phi, b_phi, W_logit, b_logit, out, B);
}